// Round 7
// baseline (158.714 us; speedup 1.0000x reference)
//
#include <hip/hip_runtime.h>

#define LOG2E 1.4426950408889634f

typedef __bf16 bf16x8 __attribute__((ext_vector_type(8)));
typedef short s16x4 __attribute__((ext_vector_type(4)));
typedef float f32x4 __attribute__((ext_vector_type(4)));

#define BB 2
#define NN 2048
#define CC 384
#define NH 12
#define HD 32
#define MROWS (BB * NN)   /* 4096 */

__device__ __forceinline__ unsigned short f2bf(float f) {
  __bf16 h = (__bf16)f;
  return __builtin_bit_cast(unsigned short, h);
}

__device__ __forceinline__ bf16x8 ldg_bf8(const unsigned short* p) {
  uint4 v = *reinterpret_cast<const uint4*>(p);
  return __builtin_bit_cast(bf16x8, v);
}

// fast 2^x: raw v_exp_f32 (args here are bounded ~±48, no denorm fixup needed)
__device__ __forceinline__ float fexp2(float x) {
#if __has_builtin(__builtin_amdgcn_exp2f)
  return __builtin_amdgcn_exp2f(x);
#else
  return exp2f(x);
#endif
}

// pack 4 floats -> 4 bf16 via v_cvt_pk_bf16_f32 when available
__device__ __forceinline__ s16x4 pack_bf4(float a, float b, float c, float d) {
#if __has_builtin(__builtin_amdgcn_cvt_pk_bf16_f32)
  auto lo = __builtin_amdgcn_cvt_pk_bf16_f32(a, b);
  auto hi = __builtin_amdgcn_cvt_pk_bf16_f32(c, d);
  uint2 u = {__builtin_bit_cast(unsigned int, lo),
             __builtin_bit_cast(unsigned int, hi)};
  return __builtin_bit_cast(s16x4, u);
#else
  s16x4 r = {(short)f2bf(a), (short)f2bf(b), (short)f2bf(c), (short)f2bf(d)};
  return r;
#endif
}

// async global->LDS DMA, 16B per lane; LDS dest = wave-uniform base + lane*16
typedef __attribute__((address_space(1))) const void gas_void;
typedef __attribute__((address_space(3))) void las_void;
__device__ __forceinline__ void gload_lds16(const void* g, void* l) {
  __builtin_amdgcn_global_load_lds((gas_void*)(unsigned long long)g,
                                   (las_void*)(unsigned long long)l, 16, 0, 0);
}

__device__ __forceinline__ f32x4 mfma32(bf16x8 a, bf16x8 b, f32x4 c) {
  return __builtin_amdgcn_mfma_f32_16x16x32_bf16(a, b, c, 0, 0, 0);
}

// 16x16x16 bf16 MFMA (A,B = 4 bf16/lane: X[m|n=lane&15][k=(lane>>4)*4+j];
// C/D: row=(lane>>4)*4+r, col=lane&15). Host pass must not see the builtin.
__device__ __forceinline__ f32x4 mfma16(s16x4 a, s16x4 b, f32x4 c) {
#if defined(__HIP_DEVICE_COMPILE__)
#if __has_builtin(__builtin_amdgcn_mfma_f32_16x16x16bf16_1k)
  return __builtin_amdgcn_mfma_f32_16x16x16bf16_1k(a, b, c, 0, 0, 0);
#else
  asm volatile("v_mfma_f32_16x16x16_bf16 %0, %1, %2, %0"
               : "+v"(c) : "v"(a), "v"(b));
  return c;
#endif
#else
  return c;  // host type-check stub
#endif
}

// ---------------- prep: fp32->bf16 casts (x + 3 weight matrices) -------------
__global__ __launch_bounds__(256) void prep_kernel(
    const float* __restrict__ x, const float* __restrict__ q_w,
    const float* __restrict__ kv_w, const float* __restrict__ proj_w,
    unsigned short* __restrict__ xb, unsigned short* __restrict__ qwb,
    unsigned short* __restrict__ kvwb, unsigned short* __restrict__ pwb) {
  int i = blockIdx.x * 256 + threadIdx.x;
  if (i < 1572864) { xb[i] = f2bf(x[i]); return; }
  i -= 1572864;
  if (i < 147456) { qwb[i] = f2bf(q_w[i]); return; }
  i -= 147456;
  if (i < 294912) { kvwb[i] = f2bf(kv_w[i]); return; }
  i -= 294912;
  pwb[i] = f2bf(proj_w[i]);
}

// ------- fused QKV GEMM + l2norm, LDS-staged (m97 structure) -----------------
// Grid (64, NH). Block tile 64M x 96N (head h: q|k|v 32-col slices), BK=64.
// LDS per buf: A 64x64 bf16 (8KB) + B 96x64 bf16 (12KB) = 20KB; double = 40KB.
__global__ __launch_bounds__(256, 4) void gemm_qkv_norm_kernel(
    const unsigned short* __restrict__ xb, const unsigned short* __restrict__ qwb,
    const unsigned short* __restrict__ kvwb, const float* __restrict__ q_b,
    const float* __restrict__ kv_b, const float* __restrict__ qe,
    const float* __restrict__ temperature, unsigned short* __restrict__ Qs,
    unsigned short* __restrict__ Kn, unsigned short* __restrict__ VT) {
  __shared__ alignas(16) char smem[2][20480];
  int wave = threadIdx.x >> 6, lane = threadIdx.x & 63;
  int c = lane & 15, quad = lane >> 4;
  int h = blockIdx.y;
  int m0b = blockIdx.x * 64;
  int cid = wave * 64 + lane;

  auto stage = [&](int buf, int kk) {
    char* base = smem[buf];
#pragma unroll
    for (int j = 0; j < 2; ++j) {  // A: 512 chunks (64 rows x 128B)
      int chunk = j * 256 + cid;
      int row = chunk >> 3, e = chunk & 7;
      gload_lds16(xb + (long)(m0b + row) * CC + kk + e * 8,
                  base + j * 4096 + wave * 1024);
    }
#pragma unroll
    for (int j = 0; j < 3; ++j) {  // B: 768 chunks (96 rows x 128B)
      int chunk = j * 256 + cid;
      int row = chunk >> 3, e = chunk & 7;
      const unsigned short* src;
      if (row < 32)      src = qwb + (long)(h * 32 + row) * CC;
      else if (row < 64) src = kvwb + (long)(h * 32 + (row - 32)) * CC;
      else               src = kvwb + (long)(CC + h * 32 + (row - 64)) * CC;
      gload_lds16(src + kk + e * 8, base + 8192 + j * 4096 + wave * 1024);
    }
  };

  f32x4 acc[6] = {};
  auto compute = [&](int buf) {
    const char* base = smem[buf];
#pragma unroll
    for (int kh = 0; kh < 2; ++kh) {
      bf16x8 a = *(const bf16x8*)(base + (wave * 16 + c) * 128 + kh * 64 + quad * 16);
#pragma unroll
      for (int t = 0; t < 6; ++t) {
        bf16x8 b = *(const bf16x8*)(base + 8192 + (t * 16 + c) * 128 + kh * 64 + quad * 16);
        acc[t] = mfma32(a, b, acc[t]);
      }
    }
  };

  stage(0, 0);
#pragma unroll 1
  for (int s = 0; s < 6; ++s) {
    __syncthreads();
    if (s < 5) stage((s + 1) & 1, (s + 1) * 64);
    compute(s & 1);
  }

  // epilogue: bias + l2norm(q,k) + qe/scale + stores
  int m0 = m0b + wave * 16;
  float qb0 = q_b[h * 32 + c], qb1 = q_b[h * 32 + 16 + c];
  float kb0 = kv_b[h * 32 + c], kb1 = kv_b[h * 32 + 16 + c];
  float vb0 = kv_b[CC + h * 32 + c], vb1 = kv_b[CC + h * 32 + 16 + c];
  float qe0 = qe[h * HD + c], qe1 = qe[h * HD + 16 + c];
  float sc = log1pf(expf(temperature[h])) * 11.0f;  // softplus * log2(N)
  int b = m0 >> 11;
  int nb = (m0 & 2047) + quad * 4;
  int pair = b * NH + h;
  unsigned short* qsb = Qs + ((long)pair * NN + nb) * HD;
  unsigned short* knb = Kn + ((long)pair * NN + nb) * HD;
  ushort4 vp0, vp1;
#pragma unroll
  for (int r = 0; r < 4; ++r) {
    float q0 = acc[0][r] + qb0, q1 = acc[1][r] + qb1;
    float k0 = acc[2][r] + kb0, k1 = acc[3][r] + kb1;
    float v0 = acc[4][r] + vb0, v1 = acc[5][r] + vb1;
    float qs = q0 * q0 + q1 * q1, ks = k0 * k0 + k1 * k1;
#pragma unroll
    for (int off = 8; off; off >>= 1) {
      qs += __shfl_xor(qs, off);
      ks += __shfl_xor(ks, off);
    }
    float qi = 1.0f / fmaxf(sqrtf(qs), 1e-12f);
    float ki = 1.0f / fmaxf(sqrtf(ks), 1e-12f);
    qsb[r * HD + c] = f2bf((q0 * qi + qe0) * sc);
    qsb[r * HD + 16 + c] = f2bf((q1 * qi + qe1) * sc);
    knb[r * HD + c] = f2bf(k0 * ki);
    knb[r * HD + 16 + c] = f2bf(k1 * ki);
    ((unsigned short*)&vp0)[r] = f2bf(v0);
    ((unsigned short*)&vp1)[r] = f2bf(v1);
  }
  *reinterpret_cast<ushort4*>(VT + ((long)pair * HD + c) * NN + nb) = vp0;
  *reinterpret_cast<ushort4*>(VT + ((long)pair * HD + 16 + c) * NN + nb) = vp1;
}

// -------- attention: S^T form, LDS-staged K/V (BK=128), conflict-free --------
// Grid (32, 24). Block = 4 waves, 64 q-rows; waves share staged K/V tiles.
// K stored in fragment-read order (lane-contiguous b128 reads); V e-major.
__global__ __launch_bounds__(256, 4) void attn_kernel(
    const unsigned short* __restrict__ Qs, const unsigned short* __restrict__ Kn,
    const unsigned short* __restrict__ VT, const float* __restrict__ pos_bias,
    unsigned short* __restrict__ ao) {
  __shared__ alignas(16) char smem[2][16384];
  int wave = threadIdx.x >> 6, lane = threadIdx.x & 63;
  int c = lane & 15, quad = lane >> 4;
  int pair = blockIdx.y, h = pair % NH, b = pair / NH;
  const unsigned short* Qp = Qs + (long)pair * NN * HD;
  const char* Kg0 = (const char*)(Kn + (long)pair * NN * HD);
  const char* Vg0 = (const char*)(VT + (long)pair * HD * NN);
  const float* bp = pos_bias + h * NN;
  int q0 = blockIdx.x * 64 + wave * 16;
  bf16x8 qf = ldg_bf8(Qp + (long)(q0 + c) * HD + quad * 8);  // B-op of S^T
  f32x4 o0 = {}, o1 = {};  // O^T: d=quad*4+r (+16), q=c
  float rs = 0.f;

  // per-lane constant source offsets for the read-order staging scatter
  const int koff = (c * 4 + quad) * 16;                        // K chunk
  const int voff = (lane & 31) * (NN * 2) + (lane >> 5) * 16;  // V e-major
  const int vro = (quad >> 1) * 512 + (quad & 1) * 8 + c * 16; // V read base

  auto stage = [&](int buf, int k0) {
    char* base = smem[buf];
    const char* Kg = Kg0 + (long)k0 * (HD * 2);
    const char* Vg = Vg0 + (long)k0 * 2;
#pragma unroll
    for (int j = 0; j < 2; ++j) {
      gload_lds16(Kg + (j * 4 + wave) * 1024 + koff,
                  base + j * 4096 + wave * 1024);
      gload_lds16(Vg + voff + j * 128 + wave * 32,
                  base + 8192 + j * 4096 + wave * 1024);
    }
  };

  auto compute = [&](int buf, int k0) {
    const char* kb = smem[buf] + lane * 16;        // lane-contig: conflict-free
    const char* vb = smem[buf] + 8192 + vro;
    const float* bq = bp + k0 + quad * 4;
#pragma unroll
    for (int t8 = 0; t8 < 8; ++t8) {
      bf16x8 kf = *(const bf16x8*)(kb + t8 * 1024);
      f32x4 z = {};
      f32x4 s = mfma32(kf, qf, z);  // S^T tile: row=k (quad*4+r), col=q (c)
      f32x4 bbv = *(const f32x4*)(bq + t8 * 16);
      float p0 = fexp2(fmaf(bbv[0], LOG2E, s[0]));
      float p1 = fexp2(fmaf(bbv[1], LOG2E, s[1]));
      float p2 = fexp2(fmaf(bbv[2], LOG2E, s[2]));
      float p3 = fexp2(fmaf(bbv[3], LOG2E, s[3]));
      rs += (p0 + p1) + (p2 + p3);
      s16x4 pf = pack_bf4(p0, p1, p2, p3);
      s16x4 vlo = *(const s16x4*)(vb + t8 * 1024);
      s16x4 vhi = *(const s16x4*)(vb + t8 * 1024 + 256);
      o0 = mfma16(vlo, pf, o0);
      o1 = mfma16(vhi, pf, o1);
    }
  };

  stage(0, 0);
#pragma unroll 1
  for (int it = 0; it < 16; ++it) {
    __syncthreads();
    if (it < 15) stage((it + 1) & 1, (it + 1) * 128);
    compute(it & 1, it * 128);
  }

  rs += __shfl_xor(rs, 16);
  rs += __shfl_xor(rs, 32);
  float inv = 1.0f / rs;
  unsigned short* op = ao + (long)(b * NN + q0 + c) * CC + h * HD + quad * 4;
  ushort4 s0, s1;
#pragma unroll
  for (int r = 0; r < 4; ++r) {
    ((unsigned short*)&s0)[r] = f2bf(o0[r] * inv);
    ((unsigned short*)&s1)[r] = f2bf(o1[r] * inv);
  }
  *reinterpret_cast<ushort4*>(op) = s0;
  *reinterpret_cast<ushort4*>(op + 16) = s1;
}

// ---------------- proj: out = ao @ proj_w^T + proj_b, LDS-staged -------------
// Grid (64, 6). Block tile 64M x 64N, BK=64. LDS: (8KB+8KB)x2 = 32KB.
__global__ __launch_bounds__(256, 4) void proj_kernel(
    const unsigned short* __restrict__ ab, const unsigned short* __restrict__ pwb,
    const float* __restrict__ proj_b, float* __restrict__ out) {
  __shared__ alignas(16) char smem[2][16384];
  int wave = threadIdx.x >> 6, lane = threadIdx.x & 63;
  int c = lane & 15, quad = lane >> 4;
  int m0b = blockIdx.x * 64;
  int n0 = blockIdx.y * 64;
  int cid = wave * 64 + lane;

  auto stage = [&](int buf, int kk) {
    char* base = smem[buf];
#pragma unroll
    for (int j = 0; j < 2; ++j) {
      int chunk = j * 256 + cid;
      int row = chunk >> 3, e = chunk & 7;
      gload_lds16(ab + (long)(m0b + row) * CC + kk + e * 8,
                  base + j * 4096 + wave * 1024);
      gload_lds16(pwb + (long)(n0 + row) * CC + kk + e * 8,
                  base + 8192 + j * 4096 + wave * 1024);
    }
  };

  f32x4 acc[4] = {};
  auto compute = [&](int buf) {
    const char* base = smem[buf];
#pragma unroll
    for (int kh = 0; kh < 2; ++kh) {
      bf16x8 a = *(const bf16x8*)(base + (wave * 16 + c) * 128 + kh * 64 + quad * 16);
#pragma unroll
      for (int t = 0; t < 4; ++t) {
        bf16x8 b = *(const bf16x8*)(base + 8192 + (t * 16 + c) * 128 + kh * 64 + quad * 16);
        acc[t] = mfma32(a, b, acc[t]);
      }
    }
  };

  stage(0, 0);
#pragma unroll 1
  for (int s = 0; s < 6; ++s) {
    __syncthreads();
    if (s < 5) stage((s + 1) & 1, (s + 1) * 64);
    compute(s & 1);
  }

  int m0 = m0b + wave * 16;
#pragma unroll
  for (int t = 0; t < 4; ++t) {
    int o = n0 + t * 16 + c;
    float bv = proj_b[o];
#pragma unroll
    for (int r = 0; r < 4; ++r) {
      out[(long)(m0 + quad * 4 + r) * CC + o] = acc[t][r] + bv;
    }
  }
}

extern "C" void kernel_launch(void* const* d_in, const int* in_sizes, int n_in,
                              void* d_out, int out_size, void* d_ws, size_t ws_size,
                              hipStream_t stream) {
  const float* x = (const float*)d_in[0];
  const float* q_w = (const float*)d_in[1];
  const float* q_b = (const float*)d_in[2];
  const float* kv_w = (const float*)d_in[3];
  const float* kv_b = (const float*)d_in[4];
  const float* qe = (const float*)d_in[5];
  const float* temp = (const float*)d_in[6];
  const float* pos_bias = (const float*)d_in[7];
  const float* proj_w = (const float*)d_in[8];
  const float* proj_b = (const float*)d_in[9];
  float* out = (float*)d_out;

  char* ws = (char*)d_ws;
  unsigned short* xb = (unsigned short*)(ws + 0);          // 3,145,728 B
  unsigned short* qwb = (unsigned short*)(ws + 3145728);   //   294,912 B
  unsigned short* kvwb = (unsigned short*)(ws + 3440640);  //   589,824 B
  unsigned short* pwb = (unsigned short*)(ws + 4030464);   //   294,912 B
  unsigned short* Qs = (unsigned short*)(ws + 4325376);    // 3,145,728 B
  unsigned short* Kn = (unsigned short*)(ws + 7471104);    // 3,145,728 B
  unsigned short* VT = (unsigned short*)(ws + 10616832);   // 3,145,728 B
  unsigned short* ao = (unsigned short*)(ws + 13762560);   // 3,145,728 B -> 16.9 MB

  prep_kernel<<<8448, 256, 0, stream>>>(x, q_w, kv_w, proj_w, xb, qwb, kvwb, pwb);
  gemm_qkv_norm_kernel<<<dim3(64, NH), 256, 0, stream>>>(xb, qwb, kvwb, q_b, kv_b,
                                                         qe, temp, Qs, Kn, VT);
  attn_kernel<<<dim3(32, 24), 256, 0, stream>>>(Qs, Kn, VT, pos_bias, ao);
  proj_kernel<<<dim3(64, 6), 256, 0, stream>>>(ao, pwb, proj_b, out);
}

// Round 8
// 133.783 us; speedup vs baseline: 1.1864x; 1.1864x over previous
//
#include <hip/hip_runtime.h>

#define LOG2E 1.4426950408889634f

typedef __bf16 bf16x8 __attribute__((ext_vector_type(8)));
typedef short s16x4 __attribute__((ext_vector_type(4)));
typedef float f32x4 __attribute__((ext_vector_type(4)));

#define BB 2
#define NN 2048
#define CC 384
#define NH 12
#define HD 32
#define MROWS (BB * NN)   /* 4096 */

__device__ __forceinline__ unsigned short f2bf(float f) {
  __bf16 h = (__bf16)f;
  return __builtin_bit_cast(unsigned short, h);
}

__device__ __forceinline__ bf16x8 ldg_bf8(const unsigned short* p) {
  uint4 v = *reinterpret_cast<const uint4*>(p);
  return __builtin_bit_cast(bf16x8, v);
}

// fast 2^x: raw v_exp_f32 (args here are bounded ~±48, no denorm fixup needed)
__device__ __forceinline__ float fexp2(float x) {
#if __has_builtin(__builtin_amdgcn_exp2f)
  return __builtin_amdgcn_exp2f(x);
#else
  return exp2f(x);
#endif
}

// pack 4 floats -> 4 bf16 via v_cvt_pk_bf16_f32 when available
__device__ __forceinline__ s16x4 pack_bf4(float a, float b, float c, float d) {
#if __has_builtin(__builtin_amdgcn_cvt_pk_bf16_f32)
  auto lo = __builtin_amdgcn_cvt_pk_bf16_f32(a, b);
  auto hi = __builtin_amdgcn_cvt_pk_bf16_f32(c, d);
  uint2 u = {__builtin_bit_cast(unsigned int, lo),
             __builtin_bit_cast(unsigned int, hi)};
  return __builtin_bit_cast(s16x4, u);
#else
  s16x4 r = {(short)f2bf(a), (short)f2bf(b), (short)f2bf(c), (short)f2bf(d)};
  return r;
#endif
}

// async global->LDS DMA, 16B per lane; LDS dest = wave-uniform base + lane*16
typedef __attribute__((address_space(1))) const void gas_void;
typedef __attribute__((address_space(3))) void las_void;
__device__ __forceinline__ void gload_lds16(const void* g, void* l) {
  __builtin_amdgcn_global_load_lds((gas_void*)(unsigned long long)g,
                                   (las_void*)(unsigned long long)l, 16, 0, 0);
}

__device__ __forceinline__ f32x4 mfma32(bf16x8 a, bf16x8 b, f32x4 c) {
  return __builtin_amdgcn_mfma_f32_16x16x32_bf16(a, b, c, 0, 0, 0);
}

// 16x16x16 bf16 MFMA (A,B = 4 bf16/lane: X[m|n=lane&15][k=(lane>>4)*4+j];
// C/D: row=(lane>>4)*4+r, col=lane&15). Host pass must not see the builtin.
__device__ __forceinline__ f32x4 mfma16(s16x4 a, s16x4 b, f32x4 c) {
#if defined(__HIP_DEVICE_COMPILE__)
#if __has_builtin(__builtin_amdgcn_mfma_f32_16x16x16bf16_1k)
  return __builtin_amdgcn_mfma_f32_16x16x16bf16_1k(a, b, c, 0, 0, 0);
#else
  asm volatile("v_mfma_f32_16x16x16_bf16 %0, %1, %2, %0"
               : "+v"(c) : "v"(a), "v"(b));
  return c;
#endif
#else
  return c;  // host type-check stub
#endif
}

// ------- prep: fp32->bf16 casts (x + 3 weights) + bias prescale by log2e -----
__global__ __launch_bounds__(256) void prep_kernel(
    const float* __restrict__ x, const float* __restrict__ q_w,
    const float* __restrict__ kv_w, const float* __restrict__ proj_w,
    const float* __restrict__ pos_bias, unsigned short* __restrict__ xb,
    unsigned short* __restrict__ qwb, unsigned short* __restrict__ kvwb,
    unsigned short* __restrict__ pwb, float* __restrict__ bias2) {
  int i = blockIdx.x * 256 + threadIdx.x;
  if (i < 1572864) { xb[i] = f2bf(x[i]); return; }
  i -= 1572864;
  if (i < 147456) { qwb[i] = f2bf(q_w[i]); return; }
  i -= 147456;
  if (i < 294912) { kvwb[i] = f2bf(kv_w[i]); return; }
  i -= 294912;
  if (i < 147456) { pwb[i] = f2bf(proj_w[i]); return; }
  i -= 147456;
  bias2[i] = pos_bias[i] * LOG2E;
}

// ------- fused QKV GEMM + l2norm, LDS-staged (m97 structure) -----------------
// Grid (64, NH). Block tile 64M x 96N (head h: q|k|v 32-col slices), BK=64.
// LDS per buf: A 64x64 bf16 (8KB) + B 96x64 bf16 (12KB) = 20KB; double = 40KB.
__global__ __launch_bounds__(256, 4) void gemm_qkv_norm_kernel(
    const unsigned short* __restrict__ xb, const unsigned short* __restrict__ qwb,
    const unsigned short* __restrict__ kvwb, const float* __restrict__ q_b,
    const float* __restrict__ kv_b, const float* __restrict__ qe,
    const float* __restrict__ temperature, unsigned short* __restrict__ Qs,
    unsigned short* __restrict__ Kn, unsigned short* __restrict__ VT) {
  __shared__ alignas(16) char smem[2][20480];
  int wave = threadIdx.x >> 6, lane = threadIdx.x & 63;
  int c = lane & 15, quad = lane >> 4;
  int h = blockIdx.y;
  int m0b = blockIdx.x * 64;
  int cid = wave * 64 + lane;

  auto stage = [&](int buf, int kk) {
    char* base = smem[buf];
#pragma unroll
    for (int j = 0; j < 2; ++j) {  // A: 512 chunks (64 rows x 128B)
      int chunk = j * 256 + cid;
      int row = chunk >> 3, e = chunk & 7;
      gload_lds16(xb + (long)(m0b + row) * CC + kk + e * 8,
                  base + j * 4096 + wave * 1024);
    }
#pragma unroll
    for (int j = 0; j < 3; ++j) {  // B: 768 chunks (96 rows x 128B)
      int chunk = j * 256 + cid;
      int row = chunk >> 3, e = chunk & 7;
      const unsigned short* src;
      if (row < 32)      src = qwb + (long)(h * 32 + row) * CC;
      else if (row < 64) src = kvwb + (long)(h * 32 + (row - 32)) * CC;
      else               src = kvwb + (long)(CC + h * 32 + (row - 64)) * CC;
      gload_lds16(src + kk + e * 8, base + 8192 + j * 4096 + wave * 1024);
    }
  };

  f32x4 acc[6] = {};
  auto compute = [&](int buf) {
    const char* base = smem[buf];
#pragma unroll
    for (int kh = 0; kh < 2; ++kh) {
      bf16x8 a = *(const bf16x8*)(base + (wave * 16 + c) * 128 + kh * 64 + quad * 16);
#pragma unroll
      for (int t = 0; t < 6; ++t) {
        bf16x8 b = *(const bf16x8*)(base + 8192 + (t * 16 + c) * 128 + kh * 64 + quad * 16);
        acc[t] = mfma32(a, b, acc[t]);
      }
    }
  };

  stage(0, 0);
#pragma unroll 1
  for (int s = 0; s < 6; ++s) {
    __syncthreads();
    if (s < 5) stage((s + 1) & 1, (s + 1) * 64);
    compute(s & 1);
  }

  // epilogue: bias + l2norm(q,k) + qe/scale + stores
  int m0 = m0b + wave * 16;
  float qb0 = q_b[h * 32 + c], qb1 = q_b[h * 32 + 16 + c];
  float kb0 = kv_b[h * 32 + c], kb1 = kv_b[h * 32 + 16 + c];
  float vb0 = kv_b[CC + h * 32 + c], vb1 = kv_b[CC + h * 32 + 16 + c];
  float qe0 = qe[h * HD + c], qe1 = qe[h * HD + 16 + c];
  float sc = log1pf(expf(temperature[h])) * 11.0f;  // softplus * log2(N)
  int b = m0 >> 11;
  int nb = (m0 & 2047) + quad * 4;
  int pair = b * NH + h;
  unsigned short* qsb = Qs + ((long)pair * NN + nb) * HD;
  unsigned short* knb = Kn + ((long)pair * NN + nb) * HD;
  ushort4 vp0, vp1;
#pragma unroll
  for (int r = 0; r < 4; ++r) {
    float q0 = acc[0][r] + qb0, q1 = acc[1][r] + qb1;
    float k0 = acc[2][r] + kb0, k1 = acc[3][r] + kb1;
    float v0 = acc[4][r] + vb0, v1 = acc[5][r] + vb1;
    float qs = q0 * q0 + q1 * q1, ks = k0 * k0 + k1 * k1;
#pragma unroll
    for (int off = 8; off; off >>= 1) {
      qs += __shfl_xor(qs, off);
      ks += __shfl_xor(ks, off);
    }
    float qi = 1.0f / fmaxf(sqrtf(qs), 1e-12f);
    float ki = 1.0f / fmaxf(sqrtf(ks), 1e-12f);
    qsb[r * HD + c] = f2bf((q0 * qi + qe0) * sc);
    qsb[r * HD + 16 + c] = f2bf((q1 * qi + qe1) * sc);
    knb[r * HD + c] = f2bf(k0 * ki);
    knb[r * HD + 16 + c] = f2bf(k1 * ki);
    ((unsigned short*)&vp0)[r] = f2bf(v0);
    ((unsigned short*)&vp1)[r] = f2bf(v1);
  }
  *reinterpret_cast<ushort4*>(VT + ((long)pair * HD + c) * NN + nb) = vp0;
  *reinterpret_cast<ushort4*>(VT + ((long)pair * HD + 16 + c) * NN + nb) = vp1;
}

// -------- attention: S^T form, LDS K/V/bias, coalesced DMA sources -----------
// Grid (32, 24). K: source-permuted within 1KB chunks -> lane-contig reads.
// V: R6 coalesced staging + XOR-swizzled 2-way reads. Bias: 8KB LDS, broadcast.
__global__ __launch_bounds__(256, 4) void attn_kernel(
    const unsigned short* __restrict__ Qs, const unsigned short* __restrict__ Kn,
    const unsigned short* __restrict__ VT, const float* __restrict__ bias2,
    unsigned short* __restrict__ ao) {
  __shared__ alignas(16) char smem[2][16384];
  __shared__ alignas(16) char biasl[8192];
  int wave = threadIdx.x >> 6, lane = threadIdx.x & 63;
  int c = lane & 15, quad = lane >> 4;
  int pair = blockIdx.y, h = pair % NH, b = pair / NH;
  const unsigned short* Qp = Qs + (long)pair * NN * HD;
  const char* Kg0 = (const char*)(Kn + (long)pair * NN * HD);
  const char* Vg0 = (const char*)(VT + (long)pair * HD * NN);
  const char* bp = (const char*)(bias2 + h * NN);
  int q0 = blockIdx.x * 64 + wave * 16;
  bf16x8 qf = ldg_bf8(Qp + (long)(q0 + c) * HD + quad * 8);  // B-op of S^T
  f32x4 o0 = {}, o1 = {};  // O^T: d=quad*4+r (+16), q=c
  float rs = 0.f;

  const int koff = (c * 4 + quad) * 16;  // K within-chunk source permutation
  const int vchunk = wave * 64 + lane;

  auto stage = [&](int buf, int k0) {
    char* base = smem[buf];
    const char* Kg = Kg0 + (long)k0 * (HD * 2);
    const char* Vg = Vg0 + (long)k0 * 2;
#pragma unroll
    for (int j = 0; j < 2; ++j) {
      gload_lds16(Kg + (j * 4 + wave) * 1024 + koff,
                  base + j * 4096 + wave * 1024);
      int chunk = j * 256 + vchunk;
      int d = chunk >> 4, e = chunk & 15;
      int es = e ^ (d & 15);  // within-row swizzle keeps source coalesced
      gload_lds16(Vg + (long)d * (NN * 2) + es * 16,
                  base + 8192 + j * 4096 + wave * 1024);
    }
  };

  auto compute = [&](int buf, int it) {
    const char* kb = smem[buf] + lane * 16;  // lane-contiguous: conflict-free
    const char* vb = smem[buf] + 8192;
    const char* bl = biasl + it * 512 + quad * 16;
#pragma unroll
    for (int t8 = 0; t8 < 8; ++t8) {
      bf16x8 kf = *(const bf16x8*)(kb + t8 * 1024);
      f32x4 z = {};
      f32x4 s = mfma32(kf, qf, z);  // S^T tile: row=k (quad*4+r), col=q (c)
      f32x4 bbv = *(const f32x4*)(bl + t8 * 64);  // broadcast (free)
      float p0 = fexp2(s[0] + bbv[0]);
      float p1 = fexp2(s[1] + bbv[1]);
      float p2 = fexp2(s[2] + bbv[2]);
      float p3 = fexp2(s[3] + bbv[3]);
      rs += (p0 + p1) + (p2 + p3);
      s16x4 pf = pack_bf4(p0, p1, p2, p3);
      int vsw = (((t8 * 2 + (quad >> 1)) ^ c) * 16) + (quad & 1) * 8;
      s16x4 vlo = *(const s16x4*)(vb + c * 256 + vsw);
      s16x4 vhi = *(const s16x4*)(vb + (c + 16) * 256 + vsw);
      o0 = mfma16(vlo, pf, o0);
      o1 = mfma16(vhi, pf, o1);
    }
  };

  // one-time bias stage (head's full 8KB) + first K/V tile
#pragma unroll
  for (int i = 0; i < 2; ++i)
    gload_lds16(bp + i * 4096 + wave * 1024 + lane * 16,
                biasl + i * 4096 + wave * 1024);
  stage(0, 0);
#pragma unroll 1
  for (int it = 0; it < 16; ++it) {
    __syncthreads();
    if (it < 15) stage((it + 1) & 1, (it + 1) * 128);
    compute(it & 1, it);
  }

  rs += __shfl_xor(rs, 16);
  rs += __shfl_xor(rs, 32);
  float inv = 1.0f / rs;
  unsigned short* op = ao + (long)(b * NN + q0 + c) * CC + h * HD + quad * 4;
  ushort4 s0, s1;
#pragma unroll
  for (int r = 0; r < 4; ++r) {
    ((unsigned short*)&s0)[r] = f2bf(o0[r] * inv);
    ((unsigned short*)&s1)[r] = f2bf(o1[r] * inv);
  }
  *reinterpret_cast<ushort4*>(op) = s0;
  *reinterpret_cast<ushort4*>(op + 16) = s1;
}

// ---------------- proj: out = ao @ proj_w^T + proj_b, LDS-staged -------------
// Grid (64, 6). Block tile 64M x 64N, BK=64. LDS: (8KB+8KB)x2 = 32KB.
__global__ __launch_bounds__(256, 4) void proj_kernel(
    const unsigned short* __restrict__ ab, const unsigned short* __restrict__ pwb,
    const float* __restrict__ proj_b, float* __restrict__ out) {
  __shared__ alignas(16) char smem[2][16384];
  int wave = threadIdx.x >> 6, lane = threadIdx.x & 63;
  int c = lane & 15, quad = lane >> 4;
  int m0b = blockIdx.x * 64;
  int n0 = blockIdx.y * 64;
  int cid = wave * 64 + lane;

  auto stage = [&](int buf, int kk) {
    char* base = smem[buf];
#pragma unroll
    for (int j = 0; j < 2; ++j) {
      int chunk = j * 256 + cid;
      int row = chunk >> 3, e = chunk & 7;
      gload_lds16(ab + (long)(m0b + row) * CC + kk + e * 8,
                  base + j * 4096 + wave * 1024);
      gload_lds16(pwb + (long)(n0 + row) * CC + kk + e * 8,
                  base + 8192 + j * 4096 + wave * 1024);
    }
  };

  f32x4 acc[4] = {};
  auto compute = [&](int buf) {
    const char* base = smem[buf];
#pragma unroll
    for (int kh = 0; kh < 2; ++kh) {
      bf16x8 a = *(const bf16x8*)(base + (wave * 16 + c) * 128 + kh * 64 + quad * 16);
#pragma unroll
      for (int t = 0; t < 4; ++t) {
        bf16x8 b = *(const bf16x8*)(base + 8192 + (t * 16 + c) * 128 + kh * 64 + quad * 16);
        acc[t] = mfma32(a, b, acc[t]);
      }
    }
  };

  stage(0, 0);
#pragma unroll 1
  for (int s = 0; s < 6; ++s) {
    __syncthreads();
    if (s < 5) stage((s + 1) & 1, (s + 1) * 64);
    compute(s & 1);
  }

  int m0 = m0b + wave * 16;
#pragma unroll
  for (int t = 0; t < 4; ++t) {
    int o = n0 + t * 16 + c;
    float bv = proj_b[o];
#pragma unroll
    for (int r = 0; r < 4; ++r) {
      out[(long)(m0 + quad * 4 + r) * CC + o] = acc[t][r] + bv;
    }
  }
}

extern "C" void kernel_launch(void* const* d_in, const int* in_sizes, int n_in,
                              void* d_out, int out_size, void* d_ws, size_t ws_size,
                              hipStream_t stream) {
  const float* x = (const float*)d_in[0];
  const float* q_w = (const float*)d_in[1];
  const float* q_b = (const float*)d_in[2];
  const float* kv_w = (const float*)d_in[3];
  const float* kv_b = (const float*)d_in[4];
  const float* qe = (const float*)d_in[5];
  const float* temp = (const float*)d_in[6];
  const float* pos_bias = (const float*)d_in[7];
  const float* proj_w = (const float*)d_in[8];
  const float* proj_b = (const float*)d_in[9];
  float* out = (float*)d_out;

  char* ws = (char*)d_ws;
  unsigned short* xb = (unsigned short*)(ws + 0);          // 3,145,728 B
  unsigned short* qwb = (unsigned short*)(ws + 3145728);   //   294,912 B
  unsigned short* kvwb = (unsigned short*)(ws + 3440640);  //   589,824 B
  unsigned short* pwb = (unsigned short*)(ws + 4030464);   //   294,912 B
  unsigned short* Qs = (unsigned short*)(ws + 4325376);    // 3,145,728 B
  unsigned short* Kn = (unsigned short*)(ws + 7471104);    // 3,145,728 B
  unsigned short* VT = (unsigned short*)(ws + 10616832);   // 3,145,728 B
  unsigned short* ao = (unsigned short*)(ws + 13762560);   // 3,145,728 B
  float* bias2 = (float*)(ws + 16908288);                  //    98,304 B -> 17 MB

  prep_kernel<<<8544, 256, 0, stream>>>(x, q_w, kv_w, proj_w, pos_bias, xb, qwb,
                                        kvwb, pwb, bias2);
  gemm_qkv_norm_kernel<<<dim3(64, NH), 256, 0, stream>>>(xb, qwb, kvwb, q_b, kv_b,
                                                         qe, temp, Qs, Kn, VT);
  attn_kernel<<<dim3(32, 24), 256, 0, stream>>>(Qs, Kn, VT, bias2, ao);
  proj_kernel<<<dim3(64, 6), 256, 0, stream>>>(ao, pwb, proj_b, out);
}

// Round 9
// 133.472 us; speedup vs baseline: 1.1891x; 1.0023x over previous
//
#include <hip/hip_runtime.h>

#define LOG2E 1.4426950408889634f

typedef __bf16 bf16x8 __attribute__((ext_vector_type(8)));
typedef short s16x4 __attribute__((ext_vector_type(4)));
typedef float f32x4 __attribute__((ext_vector_type(4)));

#define BB 2
#define NN 2048
#define CC 384
#define NH 12
#define HD 32
#define MROWS (BB * NN)   /* 4096 */

__device__ __forceinline__ unsigned short f2bf(float f) {
  __bf16 h = (__bf16)f;
  return __builtin_bit_cast(unsigned short, h);
}

__device__ __forceinline__ bf16x8 ldg_bf8(const unsigned short* p) {
  uint4 v = *reinterpret_cast<const uint4*>(p);
  return __builtin_bit_cast(bf16x8, v);
}

// fast 2^x: raw v_exp_f32 (args here are bounded ~±48, no denorm fixup needed)
__device__ __forceinline__ float fexp2(float x) {
#if __has_builtin(__builtin_amdgcn_exp2f)
  return __builtin_amdgcn_exp2f(x);
#else
  return exp2f(x);
#endif
}

// pack 4 floats -> 4 bf16 via v_cvt_pk_bf16_f32 when available
__device__ __forceinline__ s16x4 pack_bf4(float a, float b, float c, float d) {
#if __has_builtin(__builtin_amdgcn_cvt_pk_bf16_f32)
  auto lo = __builtin_amdgcn_cvt_pk_bf16_f32(a, b);
  auto hi = __builtin_amdgcn_cvt_pk_bf16_f32(c, d);
  uint2 u = {__builtin_bit_cast(unsigned int, lo),
             __builtin_bit_cast(unsigned int, hi)};
  return __builtin_bit_cast(s16x4, u);
#else
  s16x4 r = {(short)f2bf(a), (short)f2bf(b), (short)f2bf(c), (short)f2bf(d)};
  return r;
#endif
}

// async global->LDS DMA, 16B per lane; LDS dest = wave-uniform base + lane*16
typedef __attribute__((address_space(1))) const void gas_void;
typedef __attribute__((address_space(3))) void las_void;
__device__ __forceinline__ void gload_lds16(const void* g, void* l) {
  __builtin_amdgcn_global_load_lds((gas_void*)(unsigned long long)g,
                                   (las_void*)(unsigned long long)l, 16, 0, 0);
}

__device__ __forceinline__ f32x4 mfma32(bf16x8 a, bf16x8 b, f32x4 c) {
  return __builtin_amdgcn_mfma_f32_16x16x32_bf16(a, b, c, 0, 0, 0);
}

// 16x16x16 bf16 MFMA (A,B = 4 bf16/lane: X[m|n=lane&15][k=(lane>>4)*4+j];
// C/D: row=(lane>>4)*4+r, col=lane&15). Host pass must not see the builtin.
__device__ __forceinline__ f32x4 mfma16(s16x4 a, s16x4 b, f32x4 c) {
#if defined(__HIP_DEVICE_COMPILE__)
#if __has_builtin(__builtin_amdgcn_mfma_f32_16x16x16bf16_1k)
  return __builtin_amdgcn_mfma_f32_16x16x16bf16_1k(a, b, c, 0, 0, 0);
#else
  asm volatile("v_mfma_f32_16x16x16_bf16 %0, %1, %2, %0"
               : "+v"(c) : "v"(a), "v"(b));
  return c;
#endif
#else
  return c;  // host type-check stub
#endif
}

// ------- prep: fp32->bf16 casts (x + 3 weights) + bias prescale by log2e -----
__global__ __launch_bounds__(256) void prep_kernel(
    const float* __restrict__ x, const float* __restrict__ q_w,
    const float* __restrict__ kv_w, const float* __restrict__ proj_w,
    const float* __restrict__ pos_bias, unsigned short* __restrict__ xb,
    unsigned short* __restrict__ qwb, unsigned short* __restrict__ kvwb,
    unsigned short* __restrict__ pwb, float* __restrict__ bias2) {
  int i = blockIdx.x * 256 + threadIdx.x;
  if (i < 1572864) { xb[i] = f2bf(x[i]); return; }
  i -= 1572864;
  if (i < 147456) { qwb[i] = f2bf(q_w[i]); return; }
  i -= 147456;
  if (i < 294912) { kvwb[i] = f2bf(kv_w[i]); return; }
  i -= 294912;
  if (i < 147456) { pwb[i] = f2bf(proj_w[i]); return; }
  i -= 147456;
  bias2[i] = pos_bias[i] * LOG2E;
}

// ------- fused QKV GEMM + l2norm, LDS-staged (m97 structure) -----------------
// Grid (64, NH). Block tile 64M x 96N (head h: q|k|v 32-col slices), BK=64.
// LDS per buf: A 64x64 bf16 (8KB) + B 96x64 bf16 (12KB) = 20KB; double = 40KB.
__global__ __launch_bounds__(256, 4) void gemm_qkv_norm_kernel(
    const unsigned short* __restrict__ xb, const unsigned short* __restrict__ qwb,
    const unsigned short* __restrict__ kvwb, const float* __restrict__ q_b,
    const float* __restrict__ kv_b, const float* __restrict__ qe,
    const float* __restrict__ temperature, unsigned short* __restrict__ Qs,
    unsigned short* __restrict__ Kn, unsigned short* __restrict__ VT) {
  __shared__ alignas(16) char smem[2][20480];
  int wave = threadIdx.x >> 6, lane = threadIdx.x & 63;
  int c = lane & 15, quad = lane >> 4;
  int h = blockIdx.y;
  int m0b = blockIdx.x * 64;
  int cid = wave * 64 + lane;

  auto stage = [&](int buf, int kk) {
    char* base = smem[buf];
#pragma unroll
    for (int j = 0; j < 2; ++j) {  // A: 512 chunks (64 rows x 128B)
      int chunk = j * 256 + cid;
      int row = chunk >> 3, e = chunk & 7;
      gload_lds16(xb + (long)(m0b + row) * CC + kk + e * 8,
                  base + j * 4096 + wave * 1024);
    }
#pragma unroll
    for (int j = 0; j < 3; ++j) {  // B: 768 chunks (96 rows x 128B)
      int chunk = j * 256 + cid;
      int row = chunk >> 3, e = chunk & 7;
      const unsigned short* src;
      if (row < 32)      src = qwb + (long)(h * 32 + row) * CC;
      else if (row < 64) src = kvwb + (long)(h * 32 + (row - 32)) * CC;
      else               src = kvwb + (long)(CC + h * 32 + (row - 64)) * CC;
      gload_lds16(src + kk + e * 8, base + 8192 + j * 4096 + wave * 1024);
    }
  };

  f32x4 acc[6] = {};
  auto compute = [&](int buf) {
    const char* base = smem[buf];
#pragma unroll
    for (int kh = 0; kh < 2; ++kh) {
      bf16x8 a = *(const bf16x8*)(base + (wave * 16 + c) * 128 + kh * 64 + quad * 16);
#pragma unroll
      for (int t = 0; t < 6; ++t) {
        bf16x8 b = *(const bf16x8*)(base + 8192 + (t * 16 + c) * 128 + kh * 64 + quad * 16);
        acc[t] = mfma32(a, b, acc[t]);
      }
    }
  };

  stage(0, 0);
#pragma unroll 1
  for (int s = 0; s < 6; ++s) {
    __syncthreads();
    if (s < 5) stage((s + 1) & 1, (s + 1) * 64);
    compute(s & 1);
  }

  // epilogue: bias + l2norm(q,k) + qe/scale + stores
  int m0 = m0b + wave * 16;
  float qb0 = q_b[h * 32 + c], qb1 = q_b[h * 32 + 16 + c];
  float kb0 = kv_b[h * 32 + c], kb1 = kv_b[h * 32 + 16 + c];
  float vb0 = kv_b[CC + h * 32 + c], vb1 = kv_b[CC + h * 32 + 16 + c];
  float qe0 = qe[h * HD + c], qe1 = qe[h * HD + 16 + c];
  float sc = log1pf(expf(temperature[h])) * 11.0f;  // softplus * log2(N)
  int b = m0 >> 11;
  int nb = (m0 & 2047) + quad * 4;
  int pair = b * NH + h;
  unsigned short* qsb = Qs + ((long)pair * NN + nb) * HD;
  unsigned short* knb = Kn + ((long)pair * NN + nb) * HD;
  ushort4 vp0, vp1;
#pragma unroll
  for (int r = 0; r < 4; ++r) {
    float q0 = acc[0][r] + qb0, q1 = acc[1][r] + qb1;
    float k0 = acc[2][r] + kb0, k1 = acc[3][r] + kb1;
    float v0 = acc[4][r] + vb0, v1 = acc[5][r] + vb1;
    float qs = q0 * q0 + q1 * q1, ks = k0 * k0 + k1 * k1;
#pragma unroll
    for (int off = 8; off; off >>= 1) {
      qs += __shfl_xor(qs, off);
      ks += __shfl_xor(ks, off);
    }
    float qi = 1.0f / fmaxf(sqrtf(qs), 1e-12f);
    float ki = 1.0f / fmaxf(sqrtf(ks), 1e-12f);
    qsb[r * HD + c] = f2bf((q0 * qi + qe0) * sc);
    qsb[r * HD + 16 + c] = f2bf((q1 * qi + qe1) * sc);
    knb[r * HD + c] = f2bf(k0 * ki);
    knb[r * HD + 16 + c] = f2bf(k1 * ki);
    ((unsigned short*)&vp0)[r] = f2bf(v0);
    ((unsigned short*)&vp1)[r] = f2bf(v1);
  }
  *reinterpret_cast<ushort4*>(VT + ((long)pair * HD + c) * NN + nb) = vp0;
  *reinterpret_cast<ushort4*>(VT + ((long)pair * HD + 16 + c) * NN + nb) = vp1;
}

// -------- attention: S^T form, LDS K/V/bias, XCD-local pairs -----------------
// Grid 768 linear. Swizzle: pair p -> XCD p%8 (id&7 == XCD round-robin), so a
// pair's 256KB K/V is fetched from HBM once and served from its XCD's L2.
// Bias rides the QK MFMA accumulator (C rows == k indices).
__global__ __launch_bounds__(256, 4) void attn_kernel(
    const unsigned short* __restrict__ Qs, const unsigned short* __restrict__ Kn,
    const unsigned short* __restrict__ VT, const float* __restrict__ bias2,
    unsigned short* __restrict__ ao) {
  __shared__ alignas(16) char smem[2][16384];
  __shared__ alignas(16) char biasl[8192];
  int wave = threadIdx.x >> 6, lane = threadIdx.x & 63;
  int c = lane & 15, quad = lane >> 4;
  int id = blockIdx.x;
  int xcd = id & 7, rr = id >> 3;
  int pair = (rr >> 5) * 8 + xcd;   // 3 pairs per XCD
  int qt = rr & 31;
  int h = pair % NH, b = pair / NH;
  const unsigned short* Qp = Qs + (long)pair * NN * HD;
  const char* Kg0 = (const char*)(Kn + (long)pair * NN * HD);
  const char* Vg0 = (const char*)(VT + (long)pair * HD * NN);
  const char* bp = (const char*)(bias2 + h * NN);
  int q0 = qt * 64 + wave * 16;
  bf16x8 qf = ldg_bf8(Qp + (long)(q0 + c) * HD + quad * 8);  // B-op of S^T
  f32x4 o0 = {}, o1 = {};  // O^T: d=quad*4+r (+16), q=c
  float rs = 0.f;

  const int koff = (c * 4 + quad) * 16;  // K within-chunk source permutation
  const int vchunk = wave * 64 + lane;

  auto stage = [&](int buf, int k0) {
    char* base = smem[buf];
    const char* Kg = Kg0 + (long)k0 * (HD * 2);
    const char* Vg = Vg0 + (long)k0 * 2;
#pragma unroll
    for (int j = 0; j < 2; ++j) {
      gload_lds16(Kg + (j * 4 + wave) * 1024 + koff,
                  base + j * 4096 + wave * 1024);
      int chunk = j * 256 + vchunk;
      int d = chunk >> 4, e = chunk & 15;
      int es = e ^ (d & 15);  // within-row swizzle keeps source coalesced
      gload_lds16(Vg + (long)d * (NN * 2) + es * 16,
                  base + 8192 + j * 4096 + wave * 1024);
    }
  };

  auto compute = [&](int buf, int it) {
    const char* kb = smem[buf] + lane * 16;  // lane-contiguous: conflict-free
    const char* vb = smem[buf] + 8192;
    const char* bl = biasl + it * 512 + quad * 16;
#pragma unroll
    for (int t8 = 0; t8 < 8; ++t8) {
      bf16x8 kf = *(const bf16x8*)(kb + t8 * 1024);
      f32x4 bbv = *(const f32x4*)(bl + t8 * 64);  // broadcast (free)
      f32x4 s = mfma32(kf, qf, bbv);  // S^T + bias via accumulator init
      float p0 = fexp2(s[0]);
      float p1 = fexp2(s[1]);
      float p2 = fexp2(s[2]);
      float p3 = fexp2(s[3]);
      rs += (p0 + p1) + (p2 + p3);
      s16x4 pf = pack_bf4(p0, p1, p2, p3);
      int vsw = (((t8 * 2 + (quad >> 1)) ^ c) * 16) + (quad & 1) * 8;
      s16x4 vlo = *(const s16x4*)(vb + c * 256 + vsw);
      s16x4 vhi = *(const s16x4*)(vb + (c + 16) * 256 + vsw);
      o0 = mfma16(vlo, pf, o0);
      o1 = mfma16(vhi, pf, o1);
    }
  };

  // one-time bias stage (head's full 8KB) + first K/V tile
#pragma unroll
  for (int i = 0; i < 2; ++i)
    gload_lds16(bp + i * 4096 + wave * 1024 + lane * 16,
                biasl + i * 4096 + wave * 1024);
  stage(0, 0);
#pragma unroll 1
  for (int it = 0; it < 16; ++it) {
    __syncthreads();
    if (it < 15) stage((it + 1) & 1, (it + 1) * 128);
    compute(it & 1, it);
  }

  rs += __shfl_xor(rs, 16);
  rs += __shfl_xor(rs, 32);
  float inv = 1.0f / rs;
  unsigned short* op = ao + (long)(b * NN + q0 + c) * CC + h * HD + quad * 4;
  ushort4 s0, s1;
#pragma unroll
  for (int r = 0; r < 4; ++r) {
    ((unsigned short*)&s0)[r] = f2bf(o0[r] * inv);
    ((unsigned short*)&s1)[r] = f2bf(o1[r] * inv);
  }
  *reinterpret_cast<ushort4*>(op) = s0;
  *reinterpret_cast<ushort4*>(op + 16) = s1;
}

// ---------------- proj: out = ao @ proj_w^T + proj_b, LDS-staged -------------
// Grid (64, 6). Block tile 64M x 64N, BK=64. LDS: (8KB+8KB)x2 = 32KB.
__global__ __launch_bounds__(256, 4) void proj_kernel(
    const unsigned short* __restrict__ ab, const unsigned short* __restrict__ pwb,
    const float* __restrict__ proj_b, float* __restrict__ out) {
  __shared__ alignas(16) char smem[2][16384];
  int wave = threadIdx.x >> 6, lane = threadIdx.x & 63;
  int c = lane & 15, quad = lane >> 4;
  int m0b = blockIdx.x * 64;
  int n0 = blockIdx.y * 64;
  int cid = wave * 64 + lane;

  auto stage = [&](int buf, int kk) {
    char* base = smem[buf];
#pragma unroll
    for (int j = 0; j < 2; ++j) {
      int chunk = j * 256 + cid;
      int row = chunk >> 3, e = chunk & 7;
      gload_lds16(ab + (long)(m0b + row) * CC + kk + e * 8,
                  base + j * 4096 + wave * 1024);
      gload_lds16(pwb + (long)(n0 + row) * CC + kk + e * 8,
                  base + 8192 + j * 4096 + wave * 1024);
    }
  };

  f32x4 acc[4] = {};
  auto compute = [&](int buf) {
    const char* base = smem[buf];
#pragma unroll
    for (int kh = 0; kh < 2; ++kh) {
      bf16x8 a = *(const bf16x8*)(base + (wave * 16 + c) * 128 + kh * 64 + quad * 16);
#pragma unroll
      for (int t = 0; t < 4; ++t) {
        bf16x8 b = *(const bf16x8*)(base + 8192 + (t * 16 + c) * 128 + kh * 64 + quad * 16);
        acc[t] = mfma32(a, b, acc[t]);
      }
    }
  };

  stage(0, 0);
#pragma unroll 1
  for (int s = 0; s < 6; ++s) {
    __syncthreads();
    if (s < 5) stage((s + 1) & 1, (s + 1) * 64);
    compute(s & 1);
  }

  int m0 = m0b + wave * 16;
#pragma unroll
  for (int t = 0; t < 4; ++t) {
    int o = n0 + t * 16 + c;
    float bv = proj_b[o];
#pragma unroll
    for (int r = 0; r < 4; ++r) {
      out[(long)(m0 + quad * 4 + r) * CC + o] = acc[t][r] + bv;
    }
  }
}

extern "C" void kernel_launch(void* const* d_in, const int* in_sizes, int n_in,
                              void* d_out, int out_size, void* d_ws, size_t ws_size,
                              hipStream_t stream) {
  const float* x = (const float*)d_in[0];
  const float* q_w = (const float*)d_in[1];
  const float* q_b = (const float*)d_in[2];
  const float* kv_w = (const float*)d_in[3];
  const float* kv_b = (const float*)d_in[4];
  const float* qe = (const float*)d_in[5];
  const float* temp = (const float*)d_in[6];
  const float* pos_bias = (const float*)d_in[7];
  const float* proj_w = (const float*)d_in[8];
  const float* proj_b = (const float*)d_in[9];
  float* out = (float*)d_out;

  char* ws = (char*)d_ws;
  unsigned short* xb = (unsigned short*)(ws + 0);          // 3,145,728 B
  unsigned short* qwb = (unsigned short*)(ws + 3145728);   //   294,912 B
  unsigned short* kvwb = (unsigned short*)(ws + 3440640);  //   589,824 B
  unsigned short* pwb = (unsigned short*)(ws + 4030464);   //   294,912 B
  unsigned short* Qs = (unsigned short*)(ws + 4325376);    // 3,145,728 B
  unsigned short* Kn = (unsigned short*)(ws + 7471104);    // 3,145,728 B
  unsigned short* VT = (unsigned short*)(ws + 10616832);   // 3,145,728 B
  unsigned short* ao = (unsigned short*)(ws + 13762560);   // 3,145,728 B
  float* bias2 = (float*)(ws + 16908288);                  //    98,304 B -> 17 MB

  prep_kernel<<<8544, 256, 0, stream>>>(x, q_w, kv_w, proj_w, pos_bias, xb, qwb,
                                        kvwb, pwb, bias2);
  gemm_qkv_norm_kernel<<<dim3(64, NH), 256, 0, stream>>>(xb, qwb, kvwb, q_b, kv_b,
                                                         qe, temp, Qs, Kn, VT);
  attn_kernel<<<768, 256, 0, stream>>>(Qs, Kn, VT, bias2, ao);
  proj_kernel<<<dim3(64, 6), 256, 0, stream>>>(ao, pwb, proj_b, out);
}

// Round 10
// 132.504 us; speedup vs baseline: 1.1978x; 1.0073x over previous
//
#include <hip/hip_runtime.h>

#define LOG2E 1.4426950408889634f

typedef __bf16 bf16x8 __attribute__((ext_vector_type(8)));
typedef short s16x4 __attribute__((ext_vector_type(4)));
typedef float f32x4 __attribute__((ext_vector_type(4)));

#define BB 2
#define NN 2048
#define CC 384
#define NH 12
#define HD 32
#define MROWS (BB * NN)   /* 4096 */

__device__ __forceinline__ unsigned short f2bf(float f) {
  __bf16 h = (__bf16)f;
  return __builtin_bit_cast(unsigned short, h);
}

__device__ __forceinline__ bf16x8 ldg_bf8(const unsigned short* p) {
  uint4 v = *reinterpret_cast<const uint4*>(p);
  return __builtin_bit_cast(bf16x8, v);
}

// fast 2^x: raw v_exp_f32 (args here are bounded ~±48, no denorm fixup needed)
__device__ __forceinline__ float fexp2(float x) {
#if __has_builtin(__builtin_amdgcn_exp2f)
  return __builtin_amdgcn_exp2f(x);
#else
  return exp2f(x);
#endif
}

// pack 4 floats -> 4 bf16 via v_cvt_pk_bf16_f32 when available
__device__ __forceinline__ s16x4 pack_bf4(float a, float b, float c, float d) {
#if __has_builtin(__builtin_amdgcn_cvt_pk_bf16_f32)
  auto lo = __builtin_amdgcn_cvt_pk_bf16_f32(a, b);
  auto hi = __builtin_amdgcn_cvt_pk_bf16_f32(c, d);
  uint2 u = {__builtin_bit_cast(unsigned int, lo),
             __builtin_bit_cast(unsigned int, hi)};
  return __builtin_bit_cast(s16x4, u);
#else
  s16x4 r = {(short)f2bf(a), (short)f2bf(b), (short)f2bf(c), (short)f2bf(d)};
  return r;
#endif
}

// async global->LDS DMA, 16B per lane; LDS dest = wave-uniform base + lane*16
typedef __attribute__((address_space(1))) const void gas_void;
typedef __attribute__((address_space(3))) void las_void;
__device__ __forceinline__ void gload_lds16(const void* g, void* l) {
  __builtin_amdgcn_global_load_lds((gas_void*)(unsigned long long)g,
                                   (las_void*)(unsigned long long)l, 16, 0, 0);
}

__device__ __forceinline__ f32x4 mfma32(bf16x8 a, bf16x8 b, f32x4 c) {
  return __builtin_amdgcn_mfma_f32_16x16x32_bf16(a, b, c, 0, 0, 0);
}

// 16x16x16 bf16 MFMA (A,B = 4 bf16/lane: X[m|n=lane&15][k=(lane>>4)*4+j];
// C/D: row=(lane>>4)*4+r, col=lane&15). Host pass must not see the builtin.
__device__ __forceinline__ f32x4 mfma16(s16x4 a, s16x4 b, f32x4 c) {
#if defined(__HIP_DEVICE_COMPILE__)
#if __has_builtin(__builtin_amdgcn_mfma_f32_16x16x16bf16_1k)
  return __builtin_amdgcn_mfma_f32_16x16x16bf16_1k(a, b, c, 0, 0, 0);
#else
  asm volatile("v_mfma_f32_16x16x16_bf16 %0, %1, %2, %0"
               : "+v"(c) : "v"(a), "v"(b));
  return c;
#endif
#else
  return c;  // host type-check stub
#endif
}

// ------- prep: fp32->bf16 casts (x + 3 weights) + bias prescale by log2e -----
__global__ __launch_bounds__(256) void prep_kernel(
    const float* __restrict__ x, const float* __restrict__ q_w,
    const float* __restrict__ kv_w, const float* __restrict__ proj_w,
    const float* __restrict__ pos_bias, unsigned short* __restrict__ xb,
    unsigned short* __restrict__ qwb, unsigned short* __restrict__ kvwb,
    unsigned short* __restrict__ pwb, float* __restrict__ bias2) {
  int i = blockIdx.x * 256 + threadIdx.x;
  if (i < 1572864) { xb[i] = f2bf(x[i]); return; }
  i -= 1572864;
  if (i < 147456) { qwb[i] = f2bf(q_w[i]); return; }
  i -= 147456;
  if (i < 294912) { kvwb[i] = f2bf(kv_w[i]); return; }
  i -= 294912;
  if (i < 147456) { pwb[i] = f2bf(proj_w[i]); return; }
  i -= 147456;
  bias2[i] = pos_bias[i] * LOG2E;
}

// ------- fused QKV GEMM + l2norm, LDS-staged (m97 structure) -----------------
// Grid (64, NH). Block tile 64M x 96N (head h: q|k|v 32-col slices), BK=64.
__global__ __launch_bounds__(256, 4) void gemm_qkv_norm_kernel(
    const unsigned short* __restrict__ xb, const unsigned short* __restrict__ qwb,
    const unsigned short* __restrict__ kvwb, const float* __restrict__ q_b,
    const float* __restrict__ kv_b, const float* __restrict__ qe,
    const float* __restrict__ temperature, unsigned short* __restrict__ Qs,
    unsigned short* __restrict__ Kn, unsigned short* __restrict__ VT) {
  __shared__ alignas(16) char smem[2][20480];
  int wave = threadIdx.x >> 6, lane = threadIdx.x & 63;
  int c = lane & 15, quad = lane >> 4;
  int h = blockIdx.y;
  int m0b = blockIdx.x * 64;
  int cid = wave * 64 + lane;

  auto stage = [&](int buf, int kk) {
    char* base = smem[buf];
#pragma unroll
    for (int j = 0; j < 2; ++j) {  // A: 512 chunks (64 rows x 128B)
      int chunk = j * 256 + cid;
      int row = chunk >> 3, e = chunk & 7;
      gload_lds16(xb + (long)(m0b + row) * CC + kk + e * 8,
                  base + j * 4096 + wave * 1024);
    }
#pragma unroll
    for (int j = 0; j < 3; ++j) {  // B: 768 chunks (96 rows x 128B)
      int chunk = j * 256 + cid;
      int row = chunk >> 3, e = chunk & 7;
      const unsigned short* src;
      if (row < 32)      src = qwb + (long)(h * 32 + row) * CC;
      else if (row < 64) src = kvwb + (long)(h * 32 + (row - 32)) * CC;
      else               src = kvwb + (long)(CC + h * 32 + (row - 64)) * CC;
      gload_lds16(src + kk + e * 8, base + 8192 + j * 4096 + wave * 1024);
    }
  };

  f32x4 acc[6] = {};
  auto compute = [&](int buf) {
    const char* base = smem[buf];
#pragma unroll
    for (int kh = 0; kh < 2; ++kh) {
      bf16x8 a = *(const bf16x8*)(base + (wave * 16 + c) * 128 + kh * 64 + quad * 16);
#pragma unroll
      for (int t = 0; t < 6; ++t) {
        bf16x8 b = *(const bf16x8*)(base + 8192 + (t * 16 + c) * 128 + kh * 64 + quad * 16);
        acc[t] = mfma32(a, b, acc[t]);
      }
    }
  };

  stage(0, 0);
#pragma unroll 1
  for (int s = 0; s < 6; ++s) {
    __syncthreads();
    if (s < 5) stage((s + 1) & 1, (s + 1) * 64);
    compute(s & 1);
  }

  // epilogue: bias + l2norm(q,k) + qe/scale + stores
  int m0 = m0b + wave * 16;
  float qb0 = q_b[h * 32 + c], qb1 = q_b[h * 32 + 16 + c];
  float kb0 = kv_b[h * 32 + c], kb1 = kv_b[h * 32 + 16 + c];
  float vb0 = kv_b[CC + h * 32 + c], vb1 = kv_b[CC + h * 32 + 16 + c];
  float qe0 = qe[h * HD + c], qe1 = qe[h * HD + 16 + c];
  float sc = log1pf(expf(temperature[h])) * 11.0f;  // softplus * log2(N)
  int b = m0 >> 11;
  int nb = (m0 & 2047) + quad * 4;
  int pair = b * NH + h;
  unsigned short* qsb = Qs + ((long)pair * NN + nb) * HD;
  unsigned short* knb = Kn + ((long)pair * NN + nb) * HD;
  ushort4 vp0, vp1;
#pragma unroll
  for (int r = 0; r < 4; ++r) {
    float q0 = acc[0][r] + qb0, q1 = acc[1][r] + qb1;
    float k0 = acc[2][r] + kb0, k1 = acc[3][r] + kb1;
    float v0 = acc[4][r] + vb0, v1 = acc[5][r] + vb1;
    float qs = q0 * q0 + q1 * q1, ks = k0 * k0 + k1 * k1;
#pragma unroll
    for (int off = 8; off; off >>= 1) {
      qs += __shfl_xor(qs, off);
      ks += __shfl_xor(ks, off);
    }
    float qi = 1.0f / fmaxf(sqrtf(qs), 1e-12f);
    float ki = 1.0f / fmaxf(sqrtf(ks), 1e-12f);
    qsb[r * HD + c] = f2bf((q0 * qi + qe0) * sc);
    qsb[r * HD + 16 + c] = f2bf((q1 * qi + qe1) * sc);
    knb[r * HD + c] = f2bf(k0 * ki);
    knb[r * HD + 16 + c] = f2bf(k1 * ki);
    ((unsigned short*)&vp0)[r] = f2bf(v0);
    ((unsigned short*)&vp1)[r] = f2bf(v1);
  }
  *reinterpret_cast<ushort4*>(VT + ((long)pair * HD + c) * NN + nb) = vp0;
  *reinterpret_cast<ushort4*>(VT + ((long)pair * HD + 16 + c) * NN + nb) = vp1;
}

// -------- attention: S^T form, 512-thread blocks, in-block K-split x2 --------
// Grid 768 x 512. Waves 0-3: K[0,1024) for 64 q-rows; waves 4-7: K[1024,2048)
// for the SAME rows. Both halves stage + compute concurrently -> 8 barrier
// iterations instead of 16. Partials (no online max -> linear) combine in LDS.
__global__ __launch_bounds__(512, 4) void attn_kernel(
    const unsigned short* __restrict__ Qs, const unsigned short* __restrict__ Kn,
    const unsigned short* __restrict__ VT, const float* __restrict__ bias2,
    unsigned short* __restrict__ ao) {
  __shared__ alignas(16) char smem[2][2][16384];  // [buf][half][K 8KB | V 8KB]
  __shared__ alignas(16) char biasl[8192];
  int wave = threadIdx.x >> 6, lane = threadIdx.x & 63;
  int half = wave >> 2, sw = wave & 3;
  int c = lane & 15, quad = lane >> 4;
  int id = blockIdx.x;
  int xcd = id & 7, rr = id >> 3;
  int pair = (rr >> 5) * 8 + xcd;   // 3 pairs per XCD
  int qt = rr & 31;
  int h = pair % NH, b = pair / NH;
  const unsigned short* Qp = Qs + (long)pair * NN * HD;
  const char* Kg0 = (const char*)(Kn + (long)pair * NN * HD);
  const char* Vg0 = (const char*)(VT + (long)pair * HD * NN);
  const char* bp = (const char*)(bias2 + h * NN);
  int q0 = qt * 64 + sw * 16;
  bf16x8 qf = ldg_bf8(Qp + (long)(q0 + c) * HD + quad * 8);  // B-op of S^T
  f32x4 o0 = {}, o1 = {};  // O^T: d=quad*4+r (+16), q=c
  float rs = 0.f;

  const int koff = (c * 4 + quad) * 16;  // K within-chunk source permutation

  // stage iteration i (0..7) of this wave's K-half into smem[buf][half]
  auto stage = [&](int buf, int i) {
    char* tb = smem[buf][half];
    long krow0 = half * 1024 + i * 128;
    const char* Kg = Kg0 + krow0 * (HD * 2);
    const char* Vg = Vg0 + krow0 * 2;
#pragma unroll
    for (int j = 0; j < 2; ++j) {
      int ck = sw * 2 + j;  // 0..7 K-chunks of 1KB
      gload_lds16(Kg + ck * 1024 + koff, tb + ck * 1024);
      int chunk = ck * 64 + lane;  // V: 512 x 16B chunks
      int d = chunk >> 4, e = chunk & 15;
      int es = e ^ (d & 15);  // within-row swizzle keeps source coalesced
      gload_lds16(Vg + (long)d * (NN * 2) + es * 16, tb + 8192 + ck * 1024);
    }
  };

  auto compute = [&](int buf, int i) {
    const char* kb = smem[buf][half] + lane * 16;  // lane-contig: conflict-free
    const char* vb = smem[buf][half] + 8192;
    const char* bl = biasl + (half * 8 + i) * 512 + quad * 16;
#pragma unroll
    for (int t8 = 0; t8 < 8; ++t8) {
      bf16x8 kf = *(const bf16x8*)(kb + t8 * 1024);
      f32x4 bbv = *(const f32x4*)(bl + t8 * 64);  // broadcast (free)
      f32x4 s = mfma32(kf, qf, bbv);  // S^T + bias via accumulator init
      float p0 = fexp2(s[0]);
      float p1 = fexp2(s[1]);
      float p2 = fexp2(s[2]);
      float p3 = fexp2(s[3]);
      rs += (p0 + p1) + (p2 + p3);
      s16x4 pf = pack_bf4(p0, p1, p2, p3);
      int vsw = (((t8 * 2 + (quad >> 1)) ^ c) * 16) + (quad & 1) * 8;
      s16x4 vlo = *(const s16x4*)(vb + c * 256 + vsw);
      s16x4 vhi = *(const s16x4*)(vb + (c + 16) * 256 + vsw);
      o0 = mfma16(vlo, pf, o0);
      o1 = mfma16(vhi, pf, o1);
    }
  };

  // one-time bias stage (8KB, 1KB per wave) + first tiles (both halves)
  gload_lds16(bp + wave * 1024 + lane * 16, biasl + wave * 1024);
  stage(0, 0);
#pragma unroll 1
  for (int i = 0; i < 8; ++i) {
    __syncthreads();
    if (i < 7) stage((i + 1) & 1, i + 1);
    compute(i & 1, i);
  }

  // per-lane row-sum for q=c within this half
  rs += __shfl_xor(rs, 16);
  rs += __shfl_xor(rs, 32);

  // combine halves through LDS (reuse tile memory)
  __syncthreads();
  float* comb = (float*)&smem[0][0][0];  // 256 entries x 9 f32 = 9216 B
  if (half == 1) {
    float* p = comb + (sw * 64 + lane) * 9;
#pragma unroll
    for (int r = 0; r < 4; ++r) { p[r] = o0[r]; p[4 + r] = o1[r]; }
    p[8] = rs;
  }
  __syncthreads();
  if (half == 0) {
    const float* p = comb + (sw * 64 + lane) * 9;
#pragma unroll
    for (int r = 0; r < 4; ++r) { o0[r] += p[r]; o1[r] += p[4 + r]; }
    rs += p[8];
    float inv = 1.0f / rs;
    unsigned short* op = ao + (long)(b * NN + q0 + c) * CC + h * HD + quad * 4;
    ushort4 s0, s1;
#pragma unroll
    for (int r = 0; r < 4; ++r) {
      ((unsigned short*)&s0)[r] = f2bf(o0[r] * inv);
      ((unsigned short*)&s1)[r] = f2bf(o1[r] * inv);
    }
    *reinterpret_cast<ushort4*>(op) = s0;
    *reinterpret_cast<ushort4*>(op + 16) = s1;
  }
}

// ---------------- proj: out = ao @ proj_w^T + proj_b, LDS-staged -------------
// Grid (64, 6). Block tile 64M x 64N, BK=64. LDS: (8KB+8KB)x2 = 32KB.
__global__ __launch_bounds__(256, 4) void proj_kernel(
    const unsigned short* __restrict__ ab, const unsigned short* __restrict__ pwb,
    const float* __restrict__ proj_b, float* __restrict__ out) {
  __shared__ alignas(16) char smem[2][16384];
  int wave = threadIdx.x >> 6, lane = threadIdx.x & 63;
  int c = lane & 15, quad = lane >> 4;
  int m0b = blockIdx.x * 64;
  int n0 = blockIdx.y * 64;
  int cid = wave * 64 + lane;

  auto stage = [&](int buf, int kk) {
    char* base = smem[buf];
#pragma unroll
    for (int j = 0; j < 2; ++j) {
      int chunk = j * 256 + cid;
      int row = chunk >> 3, e = chunk & 7;
      gload_lds16(ab + (long)(m0b + row) * CC + kk + e * 8,
                  base + j * 4096 + wave * 1024);
      gload_lds16(pwb + (long)(n0 + row) * CC + kk + e * 8,
                  base + 8192 + j * 4096 + wave * 1024);
    }
  };

  f32x4 acc[4] = {};
  auto compute = [&](int buf) {
    const char* base = smem[buf];
#pragma unroll
    for (int kh = 0; kh < 2; ++kh) {
      bf16x8 a = *(const bf16x8*)(base + (wave * 16 + c) * 128 + kh * 64 + quad * 16);
#pragma unroll
      for (int t = 0; t < 4; ++t) {
        bf16x8 b = *(const bf16x8*)(base + 8192 + (t * 16 + c) * 128 + kh * 64 + quad * 16);
        acc[t] = mfma32(a, b, acc[t]);
      }
    }
  };

  stage(0, 0);
#pragma unroll 1
  for (int s = 0; s < 6; ++s) {
    __syncthreads();
    if (s < 5) stage((s + 1) & 1, (s + 1) * 64);
    compute(s & 1);
  }

  int m0 = m0b + wave * 16;
#pragma unroll
  for (int t = 0; t < 4; ++t) {
    int o = n0 + t * 16 + c;
    float bv = proj_b[o];
#pragma unroll
    for (int r = 0; r < 4; ++r) {
      out[(long)(m0 + quad * 4 + r) * CC + o] = acc[t][r] + bv;
    }
  }
}

extern "C" void kernel_launch(void* const* d_in, const int* in_sizes, int n_in,
                              void* d_out, int out_size, void* d_ws, size_t ws_size,
                              hipStream_t stream) {
  const float* x = (const float*)d_in[0];
  const float* q_w = (const float*)d_in[1];
  const float* q_b = (const float*)d_in[2];
  const float* kv_w = (const float*)d_in[3];
  const float* kv_b = (const float*)d_in[4];
  const float* qe = (const float*)d_in[5];
  const float* temp = (const float*)d_in[6];
  const float* pos_bias = (const float*)d_in[7];
  const float* proj_w = (const float*)d_in[8];
  const float* proj_b = (const float*)d_in[9];
  float* out = (float*)d_out;

  char* ws = (char*)d_ws;
  unsigned short* xb = (unsigned short*)(ws + 0);          // 3,145,728 B
  unsigned short* qwb = (unsigned short*)(ws + 3145728);   //   294,912 B
  unsigned short* kvwb = (unsigned short*)(ws + 3440640);  //   589,824 B
  unsigned short* pwb = (unsigned short*)(ws + 4030464);   //   294,912 B
  unsigned short* Qs = (unsigned short*)(ws + 4325376);    // 3,145,728 B
  unsigned short* Kn = (unsigned short*)(ws + 7471104);    // 3,145,728 B
  unsigned short* VT = (unsigned short*)(ws + 10616832);   // 3,145,728 B
  unsigned short* ao = (unsigned short*)(ws + 13762560);   // 3,145,728 B
  float* bias2 = (float*)(ws + 16908288);                  //    98,304 B -> 17 MB

  prep_kernel<<<8544, 256, 0, stream>>>(x, q_w, kv_w, proj_w, pos_bias, xb, qwb,
                                        kvwb, pwb, bias2);
  gemm_qkv_norm_kernel<<<dim3(64, NH), 256, 0, stream>>>(xb, qwb, kvwb, q_b, kv_b,
                                                         qe, temp, Qs, Kn, VT);
  attn_kernel<<<768, 512, 0, stream>>>(Qs, Kn, VT, bias2, ao);
  proj_kernel<<<dim3(64, 6), 256, 0, stream>>>(ao, pwb, proj_b, out);
}